// Round 7
// baseline (6050.371 us; speedup 1.0000x reference)
//
#include <hip/hip_runtime.h>
#include <hip/hip_bf16.h>
#include <math.h>

using bf16 = __hip_bfloat16;

#define NB 1024   // batch
#define NT 64     // encoder length
#define ND 512    // input size D
#define NH 512    // hidden H
#define NC 96     // classes
#define NS 21     // decode steps
#define NDC 608   // D + C
#define NG 2048   // 4H
#define GRID 1024 // persistent blocks (exactly 4/CU co-resident)

// ---- workspace layout (float offsets) ----
#define OFF_HPB   0u          /* 16,777,216 : Hp bf16 [B*T,H] */
#define OFF_BHB   16777216u   /* 16,777,216 : batch_H bf16    */
#define OFF_C     33554432u   /* 524,288    : c fp32 [B,H]    */
#define OFF_HB16  34078720u   /* 262,144    : h0 bf16 [B,H]   */
#define OFF_BAR   34340864u   /* 1,024      : 64 barrier lines (64B stride, zeroed) */
#define OFF_CTXB  34865152u   /* 262,144    : ctx bf16 [B,D]  */
#define OFF_WCB   35127296u   /* 163,840  : [Wh;Wg;pad] bf16 [640,512]      */
#define OFF_WIH2  35291136u   /* 1,048,576: [Wih[:,:512]|Whh] bf16 [2048,1024] */
#define OFF_HB2   36339712u   /* 262,144  : h1 bf16 [B,H] (ping-pong)       */
#define OFF_WIB   37224448u   /* 131,072  : Wi bf16 [512,512]               */
#define OFF_BH_   38569984u   /* 512  : bh fp32      */
#define OFF_WS_   38570496u   /* 512  : Ws fp32      */
#define OFF_BG_   38571008u   /* 96   : bg fp32      */
#define OFF_OH    38571104u   /* 196,608 : onehotT+bih+bhh fp32 [96][2048]  */
#define OFF_PHP   38767712u   /* 5,242,880 : ph/probs partials fp32 [1024][8][640] */
#define WS_NEED_FLOATS 44010592u
#define WS_NEED_BYTES ((size_t)WS_NEED_FLOATS * 4u)

typedef __attribute__((ext_vector_type(8))) short bf16x8;
typedef __attribute__((ext_vector_type(4))) float f32x4;

__device__ __forceinline__ unsigned short f2bu(float f) {
    unsigned u = __float_as_uint(f);
    unsigned r = (u + 0x7fffu + ((u >> 16) & 1u)) >> 16;  // RNE
    return (unsigned short)r;
}
__device__ __forceinline__ float b2f(short s) {
    return __uint_as_float(((unsigned)(unsigned short)s) << 16);
}
__device__ __forceinline__ float fast_sigmoid(float x) {
    return __builtin_amdgcn_rcpf(1.f + __expf(-x));
}
// tanh(x) = 1 - 2/(e^{2x}+1); saturates correctly without clamping
__device__ __forceinline__ float fast_tanh(float x) {
    return 1.f - 2.f * __builtin_amdgcn_rcpf(1.f + __expf(2.f * x));
}

// Distributed grid barrier: 64 counter lines (64B apart). Block bid arrives at
// line (bid&63) -> <=16 contenders/line (XCD-local under round-robin dispatch).
// Wave 0 polls: lane l reads line l, wave-reduce sum, compare vs bt*GRID.
// Monotonic counters; one release(wbl2) before arrive, one acquire(inv) after.
__device__ __forceinline__ void gsync(unsigned* bar, unsigned target, int bid, int tid) {
    __syncthreads();
    if (tid == 0) {
        __builtin_amdgcn_fence(__ATOMIC_RELEASE, "agent");   // publish our stores
        __hip_atomic_fetch_add(&bar[(bid & 63) * 16], 1u, __ATOMIC_RELAXED,
                               __HIP_MEMORY_SCOPE_AGENT);
    }
    if (tid < 64) {
        for (;;) {
            unsigned v = __hip_atomic_load(&bar[tid * 16], __ATOMIC_RELAXED,
                                           __HIP_MEMORY_SCOPE_AGENT);
            #pragma unroll
            for (int off = 32; off > 0; off >>= 1) v += __shfl_xor(v, off, 64);
            if (v >= target) break;
            __builtin_amdgcn_s_sleep(8);
        }
        if (tid == 0) __builtin_amdgcn_fence(__ATOMIC_ACQUIRE, "agent");  // single inv
    }
    __syncthreads();
}

// ---------------- merged conversion: batch_H -> bf16  +  weights prep ----------------
#define BH_BLOCKS 32768u   /* (1024*64*512)/(256*4) */
#define W_ELEMS   2884704u
#define W_BLOCKS  ((W_ELEMS + 255u) / 256u)

__global__ __launch_bounds__(256) void conv_all(
    const float* __restrict__ bHsrc,
    const float* __restrict__ Wi, const float* __restrict__ Wh, const float* __restrict__ bh,
    const float* __restrict__ Ws, const float* __restrict__ Wih, const float* __restrict__ Whh,
    const float* __restrict__ bih, const float* __restrict__ bhh, const float* __restrict__ Wg,
    const float* __restrict__ bg, float* __restrict__ ws) {
    if (blockIdx.x < BH_BLOCKS) {
        unsigned short* dst = (unsigned short*)(ws + OFF_BHB);
        size_t i = ((size_t)blockIdx.x * 256 + threadIdx.x) * 4;
        float4 v = *(const float4*)(bHsrc + i);
        uint2 pk;
        pk.x = (unsigned)f2bu(v.x) | ((unsigned)f2bu(v.y) << 16);
        pk.y = (unsigned)f2bu(v.z) | ((unsigned)f2bu(v.w) << 16);
        *(uint2*)&dst[i] = pk;
        return;
    }
    unsigned i = (blockIdx.x - BH_BLOCKS) * 256u + threadIdx.x;
    if (i >= W_ELEMS) return;
    unsigned short* WiB  = (unsigned short*)(ws + OFF_WIB);
    unsigned short* WcB  = (unsigned short*)(ws + OFF_WCB);
    unsigned short* Wih2 = (unsigned short*)(ws + OFF_WIH2);
    if (i < 262144u) {
        WiB[i] = f2bu(Wi[i]);
    } else if (i < 524288u) {
        unsigned j = i - 262144u;             // Wh -> combo rows 0..511
        WcB[j] = f2bu(Wh[j]);
    } else if (i < 573440u) {
        unsigned j = i - 524288u;             // Wg -> combo rows 512..607
        WcB[262144u + j] = f2bu(Wg[j]);
    } else if (i < 589824u) {
        unsigned j = i - 573440u;             // pad rows 608..639 = 0
        WcB[311296u + j] = 0;
    } else if (i < 1638400u) {
        unsigned j = i - 589824u;             // Wih[:, :512] -> Wih2 cols 0..511
        unsigned row = j >> 9, col = j & 511u;
        Wih2[row * 1024u + col] = f2bu(Wih[(size_t)row * NDC + col]);
    } else if (i < 2686976u) {
        unsigned j = i - 1638400u;            // Whh -> Wih2 cols 512..1023
        unsigned row = j >> 9, col = j & 511u;
        Wih2[row * 1024u + 512u + col] = f2bu(Whh[j]);
    } else if (i < 2687488u) {
        unsigned j = i - 2686976u;
        ws[OFF_BH_ + j] = bh[j];
    } else if (i < 2688000u) {
        unsigned j = i - 2687488u;
        ws[OFF_WS_ + j] = Ws[j];
    } else if (i < 2688096u) {
        unsigned j = i - 2688000u;
        ws[OFF_BG_ + j] = bg[j];
    } else {
        unsigned j = i - 2688096u;            // ohb[c][n] = Wih[n][512+c] + bih[n] + bhh[n]
        unsigned c = j >> 11, n = j & 2047u;
        ws[OFF_OH + j] = Wih[(size_t)n * NDC + ND + c] + bih[n] + bhh[n];
    }
}

// ---------------- Hp GEMM (bf16 MFMA, 128x128 tile) ----------------
__global__ __launch_bounds__(256) void hp_gemm(const bf16* __restrict__ A,
                                               const bf16* __restrict__ B,
                                               bf16* __restrict__ outB) {
    __shared__ short As[128 * 40];
    __shared__ short Bs[128 * 40];
    const int tid = threadIdx.x;
    const int wave = tid >> 6, lane = tid & 63;
    const int wrow = wave >> 1, wcol = wave & 1;
    const int quad = lane >> 4, l16 = lane & 15;
    const int m0 = blockIdx.x * 128, n0 = blockIdx.y * 128;
    f32x4 acc[4][4];
    #pragma unroll
    for (int mi = 0; mi < 4; ++mi)
        #pragma unroll
        for (int ni = 0; ni < 4; ++ni) acc[mi][ni] = (f32x4){0.f, 0.f, 0.f, 0.f};
    for (int k0 = 0; k0 < 512; k0 += 32) {
        #pragma unroll
        for (int l = 0; l < 2; ++l) {
            int c = tid + l * 256;
            int row = c >> 2, c8 = c & 3;
            *(uint4*)&As[row * 40 + c8 * 8] =
                *(const uint4*)&A[(size_t)(m0 + row) * 512 + k0 + c8 * 8];
            *(uint4*)&Bs[row * 40 + c8 * 8] =
                *(const uint4*)&B[(size_t)(n0 + row) * 512 + k0 + c8 * 8];
        }
        __syncthreads();
        bf16x8 af[4], bfr[4];
        #pragma unroll
        for (int mi = 0; mi < 4; ++mi)
            af[mi] = *(const bf16x8*)&As[(wrow * 64 + mi * 16 + l16) * 40 + quad * 8];
        #pragma unroll
        for (int ni = 0; ni < 4; ++ni)
            bfr[ni] = *(const bf16x8*)&Bs[(wcol * 64 + ni * 16 + l16) * 40 + quad * 8];
        #pragma unroll
        for (int mi = 0; mi < 4; ++mi)
            #pragma unroll
            for (int ni = 0; ni < 4; ++ni)
                acc[mi][ni] = __builtin_amdgcn_mfma_f32_16x16x32_bf16(af[mi], bfr[ni],
                                                                      acc[mi][ni], 0, 0, 0);
        __syncthreads();
    }
    #pragma unroll
    for (int mi = 0; mi < 4; ++mi)
        #pragma unroll
        for (int ni = 0; ni < 4; ++ni)
            #pragma unroll
            for (int r = 0; r < 4; ++r) {
                int m = m0 + wrow * 64 + mi * 16 + quad * 4 + r;
                int n = n0 + wcol * 64 + ni * 16 + l16;
                outB[(size_t)m * 512 + n] = __float2bfloat16(acc[mi][ni][r]);
            }
}

// ---------------- persistent decode loop: 21 steps, 2 distributed grid-syncs/step --------
// phase A (all 1024 blocks, b=bid): sum ph partials (+bh), emit probs row s-1 (+bg),
//   attention score/softmax/context -> ctxB.
// phase B (blocks 0..255): p = bid&7 (XCD-aligned weight slice), m0 = (bid>>3)*32.
//   gates GEMM K=1024 single-buffered (reg-staged early loads) + LSTM -> c, h_next;
//   mini-GEMM k-partial of h_next@[Wh;Wg]^T -> php[m][p][640].
__global__ __launch_bounds__(256, 4) void decode_all(
    const bf16* __restrict__ Hp, const bf16* __restrict__ bH,
    const bf16* __restrict__ Wih2, const bf16* __restrict__ WcB,
    const float* __restrict__ bh, const float* __restrict__ bg,
    const float* __restrict__ Wsv, const float* __restrict__ ohb,
    const int* __restrict__ text,
    float* __restrict__ c, bf16* __restrict__ h0g, bf16* __restrict__ h1g,
    unsigned short* __restrict__ ctxB, float* __restrict__ php,
    unsigned* __restrict__ bar, float* __restrict__ out) {
    const int bid = blockIdx.x;
    const int tid = threadIdx.x;
    const int wave = tid >> 6, lane = tid & 63;
    const int quad = lane >> 4, l16 = lane & 15;
    __shared__ float smem[9472];   // 37,888 B  (4 blocks/CU = 151,552 <= 160 KiB)
    bf16* hping[2] = {h0g, h1g};
    unsigned bt = 0;

    for (int s = 0; s < NS; ++s) {
        // ================= phase A : attention (all blocks, b = bid) =================
        {
            const int b = bid;
            float* tr = smem;            // [64][65]
            float* red = smem + 4160;    // [4][520]
            float* salpha = smem + 6240; // [64]
            float ph8[8];
            #pragma unroll
            for (int j = 0; j < 8; ++j) ph8[j] = bh[lane * 8 + j];
            if (s > 0) {
                #pragma unroll
                for (int p = 0; p < 8; ++p) {
                    const float* src = php + ((size_t)b * 8 + p) * 640 + lane * 8;
                    float4 x = *(const float4*)src, y = *(const float4*)(src + 4);
                    ph8[0] += x.x; ph8[1] += x.y; ph8[2] += x.z; ph8[3] += x.w;
                    ph8[4] += y.x; ph8[5] += y.y; ph8[6] += y.z; ph8[7] += y.w;
                }
                if (tid < NC) {
                    float v = bg[tid];
                    #pragma unroll
                    for (int p = 0; p < 8; ++p)
                        v += php[((size_t)b * 8 + p) * 640 + 512 + tid];
                    out[(size_t)b * (NS * NC) + (s - 1) * NC + tid] = v;
                }
            }
            float ws8[8];
            {
                float4 wsa = *(const float4*)(Wsv + lane * 8);
                float4 wsb = *(const float4*)(Wsv + lane * 8 + 4);
                ws8[0] = wsa.x; ws8[1] = wsa.y; ws8[2] = wsa.z; ws8[3] = wsa.w;
                ws8[4] = wsb.x; ws8[5] = wsb.y; ws8[6] = wsb.z; ws8[7] = wsb.w;
            }
            const bf16* hpb = Hp + ((size_t)b * NT + wave * 16) * NH + lane * 8;
            #pragma unroll
            for (int i = 0; i < 16; ++i) {
                bf16x8 hv = *(const bf16x8*)(hpb + (size_t)i * NH);
                float sc = 0.f;
                #pragma unroll
                for (int j = 0; j < 8; ++j) sc += fast_tanh(b2f(hv[j]) + ph8[j]) * ws8[j];
                tr[(wave * 16 + i) * 65 + lane] = sc;
            }
            __syncthreads();
            {   // partial reduce: thread (t, chunk) sums 16
                int t = tid & 63, ch = tid >> 6;
                const float* row = &tr[t * 65 + ch * 16];
                float pp = 0.f;
                #pragma unroll
                for (int j = 0; j < 16; ++j) pp += row[j];
                red[ch * 520 + t] = pp;
            }
            __syncthreads();
            if (tid < NT) {
                float e = red[tid] + red[520 + tid] + red[1040 + tid] + red[1560 + tid];
                float m = e;
                #pragma unroll
                for (int off = 32; off > 0; off >>= 1) m = fmaxf(m, __shfl_xor(m, off, 64));
                float exv = __expf(e - m);
                float ssum = exv;
                #pragma unroll
                for (int off = 32; off > 0; off >>= 1) ssum += __shfl_xor(ssum, off, 64);
                salpha[tid] = exv / ssum;
            }
            __syncthreads();
            {
                const bf16* bhp = bH + ((size_t)b * NT + wave * 16) * ND + lane * 8;
                float a8[8];
                #pragma unroll
                for (int u = 0; u < 8; ++u) a8[u] = 0.f;
                #pragma unroll
                for (int i = 0; i < 16; ++i) {
                    float al = salpha[wave * 16 + i];
                    bf16x8 v = *(const bf16x8*)(bhp + (size_t)i * ND);
                    #pragma unroll
                    for (int u = 0; u < 8; ++u) a8[u] = fmaf(al, b2f(v[u]), a8[u]);
                }
                #pragma unroll
                for (int u = 0; u < 8; ++u) red[wave * 520 + lane * 8 + u] = a8[u];
            }
            __syncthreads();
            for (int d = tid; d < ND; d += 256) {
                float sum = red[d] + red[520 + d] + red[1040 + d] + red[1560 + d];
                ctxB[(size_t)b * ND + d] = f2bu(sum);
            }
        }
        gsync(bar, (++bt) * GRID, bid, tid);
        // ================= phase B : gates + LSTM + ph/probs partials =================
        if (bid < 256) {
            short* As = (short*)smem;                  // 32*40 shorts
            short* Bs = As + 32 * 40;                  // 256*40 shorts
            float* ex = smem;                          // [4][32][65] after k-loop
            short* hlds = (short*)(smem + 8320);       // [32][72] h tile bf16
            const int g = wave;
            const int m0 = (bid >> 3) * 32;
            const int p = bid & 7;                     // XCD-aligned weight slice
            const int kp0 = p * 64;
            const int arow = tid >> 2, ac8 = tid & 3;
            const bf16* hIn = hping[s & 1];
            unsigned short* hOut = (unsigned short*)hping[(s + 1) & 1];
            const short* Wih2s = (const short*)Wih2;
            f32x4 acc[2][4];
            #pragma unroll
            for (int mi = 0; mi < 2; ++mi)
                #pragma unroll
                for (int ni = 0; ni < 4; ++ni) acc[mi][ni] = (f32x4){0.f, 0.f, 0.f, 0.f};

            uint4 rb[4]; uint4 ra;
#define STAGE_LOAD(K0)                                                         \
    {                                                                          \
        _Pragma("unroll")                                                      \
        for (int l = 0; l < 4; ++l) {                                          \
            int j = tid + l * 256;                                             \
            int row = j >> 2, c8 = j & 3;                                      \
            int brow = (row >> 6) * 512 + kp0 + (row & 63);                    \
            rb[l] = *(const uint4*)&Wih2s[(size_t)brow * 1024 + (K0) + c8 * 8];\
        }                                                                      \
        if (tid < 128) {                                                       \
            const short* srcA = ((K0) < 512)                                   \
                ? (const short*)ctxB + (size_t)(m0 + arow) * 512 + (K0) + ac8 * 8          \
                : (const short*)hIn + (size_t)(m0 + arow) * 512 + ((K0) - 512) + ac8 * 8;  \
            ra = *(const uint4*)srcA;                                          \
        }                                                                      \
    }
#define STAGE_WRITE()                                                          \
    {                                                                          \
        _Pragma("unroll")                                                      \
        for (int l = 0; l < 4; ++l) {                                          \
            int j = tid + l * 256;                                             \
            int row = j >> 2, c8 = j & 3;                                      \
            *(uint4*)&Bs[row * 40 + c8 * 8] = rb[l];                           \
        }                                                                      \
        if (tid < 128) *(uint4*)&As[arow * 40 + ac8 * 8] = ra;                 \
    }

            STAGE_LOAD(0);
            for (int it = 0; it < 32; ++it) {
                STAGE_WRITE();
                __syncthreads();
                if (it + 1 < 32) STAGE_LOAD((it + 1) * 32);  // issue early, hide under MFMA
                bf16x8 af[2], bfr[4];
                #pragma unroll
                for (int mi = 0; mi < 2; ++mi)
                    af[mi] = *(const bf16x8*)&As[(mi * 16 + l16) * 40 + quad * 8];
                #pragma unroll
                for (int ni = 0; ni < 4; ++ni)
                    bfr[ni] = *(const bf16x8*)&Bs[(g * 64 + ni * 16 + l16) * 40 + quad * 8];
                #pragma unroll
                for (int mi = 0; mi < 2; ++mi)
                    #pragma unroll
                    for (int ni = 0; ni < 4; ++ni)
                        acc[mi][ni] = __builtin_amdgcn_mfma_f32_16x16x32_bf16(
                            af[mi], bfr[ni], acc[mi][ni], 0, 0, 0);
                __syncthreads();
            }
#undef STAGE_LOAD
#undef STAGE_WRITE
            #pragma unroll
            for (int mi = 0; mi < 2; ++mi)
                #pragma unroll
                for (int ni = 0; ni < 4; ++ni)
                    #pragma unroll
                    for (int r = 0; r < 4; ++r) {
                        int ml = mi * 16 + quad * 4 + r;
                        int nl = ni * 16 + l16;
                        ex[g * 2080 + ml * 65 + nl] = acc[mi][ni][r];
                    }
            __syncthreads();
            #pragma unroll 1
            for (int t = 0; t < 8; ++t) {
                int idx = tid + t * 256;
                int ml = idx >> 6, kl = idx & 63;
                int m = m0 + ml, kp = kp0 + kl;
                int tb = text[m * NS + s];
                const float* oh = ohb + (size_t)tb * NG;   // onehot + bih + bhh
                float ig = fast_sigmoid(ex[0 * 2080 + ml * 65 + kl] + oh[kp]);
                float fg = fast_sigmoid(ex[1 * 2080 + ml * 65 + kl] + oh[NH + kp]);
                float gg = fast_tanh(ex[2 * 2080 + ml * 65 + kl] + oh[2 * NH + kp]);
                float og = fast_sigmoid(ex[3 * 2080 + ml * 65 + kl] + oh[3 * NH + kp]);
                float cn = fg * c[(size_t)m * NH + kp] + ig * gg;
                float hn = og * fast_tanh(cn);
                c[(size_t)m * NH + kp] = cn;
                unsigned short hb = f2bu(hn);
                hOut[(size_t)m * NH + kp] = hb;
                hlds[ml * 72 + kl] = (short)hb;
            }
            __syncthreads();
            // mini-GEMM: php[m][p][0..640) = h_tile(32x64k) @ WcB[:,kp-slice]^T
            #pragma unroll 1
            for (int nf = 0; nf < 10; ++nf) {
                int n0 = wave * 160 + nf * 16;
                f32x4 a0 = (f32x4){0.f, 0.f, 0.f, 0.f}, a1 = a0;
                #pragma unroll
                for (int ks = 0; ks < 2; ++ks) {
                    bf16x8 bfrg = *(const bf16x8*)((const short*)WcB +
                        (size_t)(n0 + l16) * 512 + kp0 + ks * 32 + quad * 8);
                    bf16x8 af0 = *(const bf16x8*)&hlds[l16 * 72 + ks * 32 + quad * 8];
                    bf16x8 af1 = *(const bf16x8*)&hlds[(16 + l16) * 72 + ks * 32 + quad * 8];
                    a0 = __builtin_amdgcn_mfma_f32_16x16x32_bf16(af0, bfrg, a0, 0, 0, 0);
                    a1 = __builtin_amdgcn_mfma_f32_16x16x32_bf16(af1, bfrg, a1, 0, 0, 0);
                }
                #pragma unroll
                for (int r = 0; r < 4; ++r) {
                    php[((size_t)(m0 + quad * 4 + r) * 8 + p) * 640 + n0 + l16] = a0[r];
                    php[((size_t)(m0 + 16 + quad * 4 + r) * 8 + p) * 640 + n0 + l16] = a1[r];
                }
            }
        }
        gsync(bar, (++bt) * GRID, bid, tid);
    }
    // ================= epilogue: probs row 20 from final ph partials =================
    if (tid < NC) {
        const int b = bid;
        float v = bg[tid];
        #pragma unroll
        for (int p = 0; p < 8; ++p) v += php[((size_t)b * 8 + p) * 640 + 512 + tid];
        out[(size_t)b * (NS * NC) + 20 * NC + tid] = v;
    }
}

extern "C" void kernel_launch(void* const* d_in, const int* in_sizes, int n_in,
                              void* d_out, int out_size, void* d_ws, size_t ws_size,
                              hipStream_t stream) {
    if (ws_size < WS_NEED_BYTES) {
        hipMemsetAsync(d_out, 0x7F, (size_t)out_size * 4, stream);
        return;
    }
    float* ws = (float*)d_ws;
    bf16* HpB  = (bf16*)(ws + OFF_HPB);
    bf16* bHB  = (bf16*)(ws + OFF_BHB);
    float* cb  = ws + OFF_C;
    bf16* h0   = (bf16*)(ws + OFF_HB16);
    bf16* h1   = (bf16*)(ws + OFF_HB2);
    bf16* ctxB = (bf16*)(ws + OFF_CTXB);
    bf16* WcB  = (bf16*)(ws + OFF_WCB);
    bf16* Wih2 = (bf16*)(ws + OFF_WIH2);
    bf16* WiB  = (bf16*)(ws + OFF_WIB);
    const int* text = (const int*)d_in[1];
    float* out = (float*)d_out;

    conv_all<<<BH_BLOCKS + W_BLOCKS, 256, 0, stream>>>(
        (const float*)d_in[0],
        (const float*)d_in[2], (const float*)d_in[3], (const float*)d_in[4],
        (const float*)d_in[5], (const float*)d_in[6], (const float*)d_in[7],
        (const float*)d_in[8], (const float*)d_in[9], (const float*)d_in[10],
        (const float*)d_in[11], ws);
    // zero c (fp32) + h0 (bf16) + 64 barrier lines: contiguous from OFF_C
    hipMemsetAsync(cb, 0, (size_t)787456 * 4, stream);

    // Hp(bf16) = batch_H @ Wi^T
    hp_gemm<<<dim3(NB * NT / 128, ND / 128), 256, 0, stream>>>(bHB, WiB, HpB);

    decode_all<<<GRID, 256, 0, stream>>>(
        HpB, bHB, Wih2, WcB, ws + OFF_BH_, ws + OFF_BG_, ws + OFF_WS_, ws + OFF_OH,
        text, cb, h0, h1, (unsigned short*)ctxB, ws + OFF_PHP,
        (unsigned*)(ws + OFF_BAR), out);
}

// Round 8
// 5393.041 us; speedup vs baseline: 1.1219x; 1.1219x over previous
//
#include <hip/hip_runtime.h>
#include <hip/hip_bf16.h>
#include <math.h>

using bf16 = __hip_bfloat16;

#define NB 1024   // batch
#define NT 64     // encoder length
#define ND 512    // input size D
#define NH 512    // hidden H
#define NC 96     // classes
#define NS 21     // decode steps
#define NDC 608   // D + C
#define NG 2048   // 4H
#define GRID 1024 // persistent blocks (exactly 4/CU co-resident)

// ---- workspace layout (float offsets) ----
#define OFF_HPB   0u          /* 16,777,216 : Hp bf16 [B*T,H] */
#define OFF_BHB   16777216u   /* 16,777,216 : batch_H bf16    */
#define OFF_C     33554432u   /* 524,288    : c fp32 [B,H]    */
#define OFF_HB16  34078720u   /* 262,144    : h0 bf16 [B,H]   */
#define OFF_BAR   34340864u   /* 1,024      : 64 barrier lines (64B stride, zeroed) */
#define OFF_CTXB  34865152u   /* 262,144    : ctx bf16 [B,D]  */
#define OFF_WCB   35127296u   /* 163,840  : [Wh;Wg;pad] bf16 [640,512]      */
#define OFF_WIH2  35291136u   /* 1,048,576: [Wih[:,:512]|Whh] bf16 [2048,1024] */
#define OFF_HB2   36339712u   /* 262,144  : h1 bf16 [B,H] (ping-pong)       */
#define OFF_WIB   37224448u   /* 131,072  : Wi bf16 [512,512]               */
#define OFF_BH_   38569984u   /* 512  : bh fp32      */
#define OFF_WS_   38570496u   /* 512  : Ws fp32      */
#define OFF_BG_   38571008u   /* 96   : bg fp32      */
#define OFF_OH    38571104u   /* 196,608 : onehotT+bih+bhh fp32 [96][2048]  */
#define OFF_PHP   38767712u   /* 5,242,880 : ph/probs partials fp32 [1024][8][640] */
#define WS_NEED_FLOATS 44010592u
#define WS_NEED_BYTES ((size_t)WS_NEED_FLOATS * 4u)

typedef __attribute__((ext_vector_type(8))) short bf16x8;
typedef __attribute__((ext_vector_type(4))) float f32x4;

__device__ __forceinline__ unsigned short f2bu(float f) {
    unsigned u = __float_as_uint(f);
    unsigned r = (u + 0x7fffu + ((u >> 16) & 1u)) >> 16;  // RNE
    return (unsigned short)r;
}
__device__ __forceinline__ float b2f(short s) {
    return __uint_as_float(((unsigned)(unsigned short)s) << 16);
}
__device__ __forceinline__ float fast_sigmoid(float x) {
    return __builtin_amdgcn_rcpf(1.f + __expf(-x));
}
// tanh(x) = 1 - 2/(e^{2x}+1); saturates correctly without clamping
__device__ __forceinline__ float fast_tanh(float x) {
    return 1.f - 2.f * __builtin_amdgcn_rcpf(1.f + __expf(2.f * x));
}

// Coherence-point accesses (sc0 sc1): bypass L1/L2, read/write memory-side L3.
// Used ONLY for cross-block mutable data (ctxB, h ping-pong, php). This removes
// the need for any buffer_wbl2/buffer_inv cache maintenance at grid barriers.
__device__ __forceinline__ float ldcg(const float* p) {
    return __hip_atomic_load(p, __ATOMIC_RELAXED, __HIP_MEMORY_SCOPE_AGENT);
}
__device__ __forceinline__ void stcg(float* p, float v) {
    __hip_atomic_store(p, v, __ATOMIC_RELAXED, __HIP_MEMORY_SCOPE_AGENT);
}
__device__ __forceinline__ unsigned ldcg_u(const unsigned* p) {
    return __hip_atomic_load(p, __ATOMIC_RELAXED, __HIP_MEMORY_SCOPE_AGENT);
}
__device__ __forceinline__ void stcg_u(unsigned* p, unsigned v) {
    __hip_atomic_store(p, v, __ATOMIC_RELAXED, __HIP_MEMORY_SCOPE_AGENT);
}

// Distributed fence-free grid barrier: 64 counter lines (64B apart). Block bid
// arrives at line (bid&63); wave 0 polls all 64 lines (one per lane) and
// wave-reduces. __syncthreads() drains vmcnt (compiler emits full waitcnt
// before s_barrier) so all coherent stores reached L3 before arrival.
__device__ __forceinline__ void gsync(unsigned* bar, unsigned target, int bid, int tid) {
    __syncthreads();
    if (tid == 0)
        __hip_atomic_fetch_add(&bar[(bid & 63) * 16], 1u, __ATOMIC_RELAXED,
                               __HIP_MEMORY_SCOPE_AGENT);
    if (tid < 64) {
        for (;;) {
            unsigned v = __hip_atomic_load(&bar[tid * 16], __ATOMIC_RELAXED,
                                           __HIP_MEMORY_SCOPE_AGENT);
            #pragma unroll
            for (int off = 32; off > 0; off >>= 1) v += __shfl_xor(v, off, 64);
            if (v >= target) break;
            __builtin_amdgcn_s_sleep(8);
        }
    }
    __syncthreads();
}

// ---------------- merged conversion: batch_H -> bf16  +  weights prep ----------------
#define BH_BLOCKS 32768u   /* (1024*64*512)/(256*4) */
#define W_ELEMS   2884704u
#define W_BLOCKS  ((W_ELEMS + 255u) / 256u)

__global__ __launch_bounds__(256) void conv_all(
    const float* __restrict__ bHsrc,
    const float* __restrict__ Wi, const float* __restrict__ Wh, const float* __restrict__ bh,
    const float* __restrict__ Ws, const float* __restrict__ Wih, const float* __restrict__ Whh,
    const float* __restrict__ bih, const float* __restrict__ bhh, const float* __restrict__ Wg,
    const float* __restrict__ bg, float* __restrict__ ws) {
    if (blockIdx.x < BH_BLOCKS) {
        unsigned short* dst = (unsigned short*)(ws + OFF_BHB);
        size_t i = ((size_t)blockIdx.x * 256 + threadIdx.x) * 4;
        float4 v = *(const float4*)(bHsrc + i);
        uint2 pk;
        pk.x = (unsigned)f2bu(v.x) | ((unsigned)f2bu(v.y) << 16);
        pk.y = (unsigned)f2bu(v.z) | ((unsigned)f2bu(v.w) << 16);
        *(uint2*)&dst[i] = pk;
        return;
    }
    unsigned i = (blockIdx.x - BH_BLOCKS) * 256u + threadIdx.x;
    if (i >= W_ELEMS) return;
    unsigned short* WiB  = (unsigned short*)(ws + OFF_WIB);
    unsigned short* WcB  = (unsigned short*)(ws + OFF_WCB);
    unsigned short* Wih2 = (unsigned short*)(ws + OFF_WIH2);
    if (i < 262144u) {
        WiB[i] = f2bu(Wi[i]);
    } else if (i < 524288u) {
        unsigned j = i - 262144u;             // Wh -> combo rows 0..511
        WcB[j] = f2bu(Wh[j]);
    } else if (i < 573440u) {
        unsigned j = i - 524288u;             // Wg -> combo rows 512..607
        WcB[262144u + j] = f2bu(Wg[j]);
    } else if (i < 589824u) {
        unsigned j = i - 573440u;             // pad rows 608..639 = 0
        WcB[311296u + j] = 0;
    } else if (i < 1638400u) {
        unsigned j = i - 589824u;             // Wih[:, :512] -> Wih2 cols 0..511
        unsigned row = j >> 9, col = j & 511u;
        Wih2[row * 1024u + col] = f2bu(Wih[(size_t)row * NDC + col]);
    } else if (i < 2686976u) {
        unsigned j = i - 1638400u;            // Whh -> Wih2 cols 512..1023
        unsigned row = j >> 9, col = j & 511u;
        Wih2[row * 1024u + 512u + col] = f2bu(Whh[j]);
    } else if (i < 2687488u) {
        unsigned j = i - 2686976u;
        ws[OFF_BH_ + j] = bh[j];
    } else if (i < 2688000u) {
        unsigned j = i - 2687488u;
        ws[OFF_WS_ + j] = Ws[j];
    } else if (i < 2688096u) {
        unsigned j = i - 2688000u;
        ws[OFF_BG_ + j] = bg[j];
    } else {
        unsigned j = i - 2688096u;            // ohb[c][n] = Wih[n][512+c] + bih[n] + bhh[n]
        unsigned c = j >> 11, n = j & 2047u;
        ws[OFF_OH + j] = Wih[(size_t)n * NDC + ND + c] + bih[n] + bhh[n];
    }
}

// ---------------- Hp GEMM (bf16 MFMA, 128x128 tile) ----------------
__global__ __launch_bounds__(256) void hp_gemm(const bf16* __restrict__ A,
                                               const bf16* __restrict__ B,
                                               bf16* __restrict__ outB) {
    __shared__ short As[128 * 40];
    __shared__ short Bs[128 * 40];
    const int tid = threadIdx.x;
    const int wave = tid >> 6, lane = tid & 63;
    const int wrow = wave >> 1, wcol = wave & 1;
    const int quad = lane >> 4, l16 = lane & 15;
    const int m0 = blockIdx.x * 128, n0 = blockIdx.y * 128;
    f32x4 acc[4][4];
    #pragma unroll
    for (int mi = 0; mi < 4; ++mi)
        #pragma unroll
        for (int ni = 0; ni < 4; ++ni) acc[mi][ni] = (f32x4){0.f, 0.f, 0.f, 0.f};
    for (int k0 = 0; k0 < 512; k0 += 32) {
        #pragma unroll
        for (int l = 0; l < 2; ++l) {
            int c = tid + l * 256;
            int row = c >> 2, c8 = c & 3;
            *(uint4*)&As[row * 40 + c8 * 8] =
                *(const uint4*)&A[(size_t)(m0 + row) * 512 + k0 + c8 * 8];
            *(uint4*)&Bs[row * 40 + c8 * 8] =
                *(const uint4*)&B[(size_t)(n0 + row) * 512 + k0 + c8 * 8];
        }
        __syncthreads();
        bf16x8 af[4], bfr[4];
        #pragma unroll
        for (int mi = 0; mi < 4; ++mi)
            af[mi] = *(const bf16x8*)&As[(wrow * 64 + mi * 16 + l16) * 40 + quad * 8];
        #pragma unroll
        for (int ni = 0; ni < 4; ++ni)
            bfr[ni] = *(const bf16x8*)&Bs[(wcol * 64 + ni * 16 + l16) * 40 + quad * 8];
        #pragma unroll
        for (int mi = 0; mi < 4; ++mi)
            #pragma unroll
            for (int ni = 0; ni < 4; ++ni)
                acc[mi][ni] = __builtin_amdgcn_mfma_f32_16x16x32_bf16(af[mi], bfr[ni],
                                                                      acc[mi][ni], 0, 0, 0);
        __syncthreads();
    }
    #pragma unroll
    for (int mi = 0; mi < 4; ++mi)
        #pragma unroll
        for (int ni = 0; ni < 4; ++ni)
            #pragma unroll
            for (int r = 0; r < 4; ++r) {
                int m = m0 + wrow * 64 + mi * 16 + quad * 4 + r;
                int n = n0 + wcol * 64 + ni * 16 + l16;
                outB[(size_t)m * 512 + n] = __float2bfloat16(acc[mi][ni][r]);
            }
}

// ---------------- persistent decode loop: fence-free barriers, coherent shared data ------
__global__ __launch_bounds__(256, 4) void decode_all(
    const bf16* __restrict__ Hp, const bf16* __restrict__ bH,
    const bf16* __restrict__ Wih2, const bf16* __restrict__ WcB,
    const float* __restrict__ bh, const float* __restrict__ bg,
    const float* __restrict__ Wsv, const float* __restrict__ ohb,
    const int* __restrict__ text,
    float* __restrict__ c, bf16* __restrict__ h0g, bf16* __restrict__ h1g,
    unsigned short* __restrict__ ctxB, float* __restrict__ php,
    unsigned* __restrict__ bar, float* __restrict__ out) {
    const int bid = blockIdx.x;
    const int tid = threadIdx.x;
    const int wave = tid >> 6, lane = tid & 63;
    const int quad = lane >> 4, l16 = lane & 15;
    __shared__ float smem[9472];   // 37,888 B  (4 blocks/CU = 151,552 <= 160 KiB)
    bf16* hping[2] = {h0g, h1g};
    unsigned bt = 0;

    for (int s = 0; s < NS; ++s) {
        // ================= phase A : attention (all blocks, b = bid) =================
        {
            const int b = bid;
            float* tr = smem;            // [64][65]
            float* red = smem + 4160;    // [4][520]
            float* salpha = smem + 6240; // [64]
            float ph8[8];
            #pragma unroll
            for (int j = 0; j < 8; ++j) ph8[j] = bh[lane * 8 + j];
            if (s > 0) {
                #pragma unroll
                for (int p = 0; p < 8; ++p) {
                    const float* src = php + ((size_t)b * 8 + p) * 640 + lane * 8;
                    #pragma unroll
                    for (int j = 0; j < 8; ++j) ph8[j] += ldcg(src + j);
                }
                if (tid < NC) {
                    float v = bg[tid];
                    #pragma unroll
                    for (int p = 0; p < 8; ++p)
                        v += ldcg(&php[((size_t)b * 8 + p) * 640 + 512 + tid]);
                    out[(size_t)b * (NS * NC) + (s - 1) * NC + tid] = v;
                }
            }
            float ws8[8];
            {
                float4 wsa = *(const float4*)(Wsv + lane * 8);
                float4 wsb = *(const float4*)(Wsv + lane * 8 + 4);
                ws8[0] = wsa.x; ws8[1] = wsa.y; ws8[2] = wsa.z; ws8[3] = wsa.w;
                ws8[4] = wsb.x; ws8[5] = wsb.y; ws8[6] = wsb.z; ws8[7] = wsb.w;
            }
            const bf16* hpb = Hp + ((size_t)b * NT + wave * 16) * NH + lane * 8;
            #pragma unroll
            for (int i = 0; i < 16; ++i) {
                bf16x8 hv = *(const bf16x8*)(hpb + (size_t)i * NH);
                float sc = 0.f;
                #pragma unroll
                for (int j = 0; j < 8; ++j) sc += fast_tanh(b2f(hv[j]) + ph8[j]) * ws8[j];
                tr[(wave * 16 + i) * 65 + lane] = sc;
            }
            __syncthreads();
            {   // partial reduce: thread (t, chunk) sums 16
                int t = tid & 63, ch = tid >> 6;
                const float* row = &tr[t * 65 + ch * 16];
                float pp = 0.f;
                #pragma unroll
                for (int j = 0; j < 16; ++j) pp += row[j];
                red[ch * 520 + t] = pp;
            }
            __syncthreads();
            if (tid < NT) {
                float e = red[tid] + red[520 + tid] + red[1040 + tid] + red[1560 + tid];
                float m = e;
                #pragma unroll
                for (int off = 32; off > 0; off >>= 1) m = fmaxf(m, __shfl_xor(m, off, 64));
                float exv = __expf(e - m);
                float ssum = exv;
                #pragma unroll
                for (int off = 32; off > 0; off >>= 1) ssum += __shfl_xor(ssum, off, 64);
                salpha[tid] = exv / ssum;
            }
            __syncthreads();
            {
                const bf16* bhp = bH + ((size_t)b * NT + wave * 16) * ND + lane * 8;
                float a8[8];
                #pragma unroll
                for (int u = 0; u < 8; ++u) a8[u] = 0.f;
                #pragma unroll
                for (int i = 0; i < 16; ++i) {
                    float al = salpha[wave * 16 + i];
                    bf16x8 v = *(const bf16x8*)(bhp + (size_t)i * ND);
                    #pragma unroll
                    for (int u = 0; u < 8; ++u) a8[u] = fmaf(al, b2f(v[u]), a8[u]);
                }
                #pragma unroll
                for (int u = 0; u < 8; ++u) red[wave * 520 + lane * 8 + u] = a8[u];
            }
            __syncthreads();
            {   // ctx write: 2 consecutive d per thread, packed coherent uint store
                int d = tid * 2;
                float s0 = red[d] + red[520 + d] + red[1040 + d] + red[1560 + d];
                float s1 = red[d + 1] + red[520 + d + 1] + red[1040 + d + 1] + red[1560 + d + 1];
                unsigned pk = (unsigned)f2bu(s0) | ((unsigned)f2bu(s1) << 16);
                stcg_u((unsigned*)ctxB + ((size_t)b * ND + d) / 2, pk);
            }
        }
        gsync(bar, (++bt) * GRID, bid, tid);
        // ================= phase B : gates + LSTM + ph/probs partials =================
        if (bid < 256) {
            short* As = (short*)smem;                  // 32*40 shorts
            short* Bs = As + 32 * 40;                  // 256*40 shorts
            float* ex = smem;                          // [4][32][65] after k-loop
            short* hlds = (short*)(smem + 8320);       // [32][72] h tile bf16
            const int g = wave;
            const int m0 = (bid >> 3) * 32;
            const int p = bid & 7;                     // XCD-aligned weight slice
            const int kp0 = p * 64;
            const int arow = tid >> 2, ac8 = tid & 3;
            const bf16* hIn = hping[s & 1];
            unsigned short* hOut = (unsigned short*)hping[(s + 1) & 1];
            const short* Wih2s = (const short*)Wih2;
            f32x4 acc[2][4];
            #pragma unroll
            for (int mi = 0; mi < 2; ++mi)
                #pragma unroll
                for (int ni = 0; ni < 4; ++ni) acc[mi][ni] = (f32x4){0.f, 0.f, 0.f, 0.f};

            uint4 rb[4]; uint4 ra;
#define STAGE_LOAD(K0)                                                         \
    {                                                                          \
        _Pragma("unroll")                                                      \
        for (int l = 0; l < 4; ++l) {                                          \
            int j = tid + l * 256;                                             \
            int row = j >> 2, c8 = j & 3;                                      \
            int brow = (row >> 6) * 512 + kp0 + (row & 63);                    \
            rb[l] = *(const uint4*)&Wih2s[(size_t)brow * 1024 + (K0) + c8 * 8];\
        }                                                                      \
        if (tid < 128) {                                                       \
            const unsigned* srcA = ((K0) < 512)                                \
                ? (const unsigned*)ctxB + ((size_t)(m0 + arow) * 512 + (K0)) / 2 + ac8 * 4         \
                : (const unsigned*)hIn + ((size_t)(m0 + arow) * 512 + ((K0) - 512)) / 2 + ac8 * 4; \
            ra.x = ldcg_u(srcA);     ra.y = ldcg_u(srcA + 1);                  \
            ra.z = ldcg_u(srcA + 2); ra.w = ldcg_u(srcA + 3);                  \
        }                                                                      \
    }
#define STAGE_WRITE()                                                          \
    {                                                                          \
        _Pragma("unroll")                                                      \
        for (int l = 0; l < 4; ++l) {                                          \
            int j = tid + l * 256;                                             \
            int row = j >> 2, c8 = j & 3;                                      \
            *(uint4*)&Bs[row * 40 + c8 * 8] = rb[l];                           \
        }                                                                      \
        if (tid < 128) *(uint4*)&As[arow * 40 + ac8 * 8] = ra;                 \
    }

            STAGE_LOAD(0);
            for (int it = 0; it < 32; ++it) {
                STAGE_WRITE();
                __syncthreads();
                if (it + 1 < 32) STAGE_LOAD((it + 1) * 32);  // issue early, hide under MFMA
                bf16x8 af[2], bfr[4];
                #pragma unroll
                for (int mi = 0; mi < 2; ++mi)
                    af[mi] = *(const bf16x8*)&As[(mi * 16 + l16) * 40 + quad * 8];
                #pragma unroll
                for (int ni = 0; ni < 4; ++ni)
                    bfr[ni] = *(const bf16x8*)&Bs[(g * 64 + ni * 16 + l16) * 40 + quad * 8];
                #pragma unroll
                for (int mi = 0; mi < 2; ++mi)
                    #pragma unroll
                    for (int ni = 0; ni < 4; ++ni)
                        acc[mi][ni] = __builtin_amdgcn_mfma_f32_16x16x32_bf16(
                            af[mi], bfr[ni], acc[mi][ni], 0, 0, 0);
                __syncthreads();
            }
#undef STAGE_LOAD
#undef STAGE_WRITE
            #pragma unroll
            for (int mi = 0; mi < 2; ++mi)
                #pragma unroll
                for (int ni = 0; ni < 4; ++ni)
                    #pragma unroll
                    for (int r = 0; r < 4; ++r) {
                        int ml = mi * 16 + quad * 4 + r;
                        int nl = ni * 16 + l16;
                        ex[g * 2080 + ml * 65 + nl] = acc[mi][ni][r];
                    }
            __syncthreads();
            #pragma unroll 1
            for (int t = 0; t < 4; ++t) {
                int idx = tid + t * 256;
                int ml = idx >> 5, klp = (idx & 31) * 2;
                int m = m0 + ml, kp = kp0 + klp;
                int tb = text[m * NS + s];
                const float* oh = ohb + (size_t)tb * NG;   // onehot + bih + bhh
                float2 cc = *(const float2*)&c[(size_t)m * NH + kp];
                float ig0 = fast_sigmoid(ex[0 * 2080 + ml * 65 + klp] + oh[kp]);
                float fg0 = fast_sigmoid(ex[1 * 2080 + ml * 65 + klp] + oh[NH + kp]);
                float gg0 = fast_tanh(ex[2 * 2080 + ml * 65 + klp] + oh[2 * NH + kp]);
                float og0 = fast_sigmoid(ex[3 * 2080 + ml * 65 + klp] + oh[3 * NH + kp]);
                float cn0 = fg0 * cc.x + ig0 * gg0;
                float hn0 = og0 * fast_tanh(cn0);
                float ig1 = fast_sigmoid(ex[0 * 2080 + ml * 65 + klp + 1] + oh[kp + 1]);
                float fg1 = fast_sigmoid(ex[1 * 2080 + ml * 65 + klp + 1] + oh[NH + kp + 1]);
                float gg1 = fast_tanh(ex[2 * 2080 + ml * 65 + klp + 1] + oh[2 * NH + kp + 1]);
                float og1 = fast_sigmoid(ex[3 * 2080 + ml * 65 + klp + 1] + oh[3 * NH + kp + 1]);
                float cn1 = fg1 * cc.y + ig1 * gg1;
                float hn1 = og1 * fast_tanh(cn1);
                *(float2*)&c[(size_t)m * NH + kp] = (float2){cn0, cn1};
                unsigned hpk = (unsigned)f2bu(hn0) | ((unsigned)f2bu(hn1) << 16);
                stcg_u((unsigned*)hOut + ((size_t)m * NH + kp) / 2, hpk);
                *(unsigned*)&hlds[ml * 72 + klp] = hpk;
            }
            __syncthreads();
            // mini-GEMM: php[m][p][0..640) = h_tile(32x64k) @ WcB[:,kp-slice]^T
            #pragma unroll 1
            for (int nf = 0; nf < 10; ++nf) {
                int n0 = wave * 160 + nf * 16;
                f32x4 a0 = (f32x4){0.f, 0.f, 0.f, 0.f}, a1 = a0;
                #pragma unroll
                for (int ks = 0; ks < 2; ++ks) {
                    bf16x8 bfrg = *(const bf16x8*)((const short*)WcB +
                        (size_t)(n0 + l16) * 512 + kp0 + ks * 32 + quad * 8);
                    bf16x8 af0 = *(const bf16x8*)&hlds[l16 * 72 + ks * 32 + quad * 8];
                    bf16x8 af1 = *(const bf16x8*)&hlds[(16 + l16) * 72 + ks * 32 + quad * 8];
                    a0 = __builtin_amdgcn_mfma_f32_16x16x32_bf16(af0, bfrg, a0, 0, 0, 0);
                    a1 = __builtin_amdgcn_mfma_f32_16x16x32_bf16(af1, bfrg, a1, 0, 0, 0);
                }
                #pragma unroll
                for (int r = 0; r < 4; ++r) {
                    stcg(&php[((size_t)(m0 + quad * 4 + r) * 8 + p) * 640 + n0 + l16], a0[r]);
                    stcg(&php[((size_t)(m0 + 16 + quad * 4 + r) * 8 + p) * 640 + n0 + l16], a1[r]);
                }
            }
        }
        gsync(bar, (++bt) * GRID, bid, tid);
    }
    // ================= epilogue: probs row 20 from final ph partials =================
    if (tid < NC) {
        const int b = bid;
        float v = bg[tid];
        #pragma unroll
        for (int p = 0; p < 8; ++p) v += ldcg(&php[((size_t)b * 8 + p) * 640 + 512 + tid]);
        out[(size_t)b * (NS * NC) + 20 * NC + tid] = v;
    }
}

extern "C" void kernel_launch(void* const* d_in, const int* in_sizes, int n_in,
                              void* d_out, int out_size, void* d_ws, size_t ws_size,
                              hipStream_t stream) {
    if (ws_size < WS_NEED_BYTES) {
        hipMemsetAsync(d_out, 0x7F, (size_t)out_size * 4, stream);
        return;
    }
    float* ws = (float*)d_ws;
    bf16* HpB  = (bf16*)(ws + OFF_HPB);
    bf16* bHB  = (bf16*)(ws + OFF_BHB);
    float* cb  = ws + OFF_C;
    bf16* h0   = (bf16*)(ws + OFF_HB16);
    bf16* h1   = (bf16*)(ws + OFF_HB2);
    bf16* ctxB = (bf16*)(ws + OFF_CTXB);
    bf16* WcB  = (bf16*)(ws + OFF_WCB);
    bf16* Wih2 = (bf16*)(ws + OFF_WIH2);
    bf16* WiB  = (bf16*)(ws + OFF_WIB);
    const int* text = (const int*)d_in[1];
    float* out = (float*)d_out;

    conv_all<<<BH_BLOCKS + W_BLOCKS, 256, 0, stream>>>(
        (const float*)d_in[0],
        (const float*)d_in[2], (const float*)d_in[3], (const float*)d_in[4],
        (const float*)d_in[5], (const float*)d_in[6], (const float*)d_in[7],
        (const float*)d_in[8], (const float*)d_in[9], (const float*)d_in[10],
        (const float*)d_in[11], ws);
    // zero c (fp32) + h0 (bf16) + 64 barrier lines: contiguous from OFF_C
    hipMemsetAsync(cb, 0, (size_t)787456 * 4, stream);

    // Hp(bf16) = batch_H @ Wi^T
    hp_gemm<<<dim3(NB * NT / 128, ND / 128), 256, 0, stream>>>(bHB, WiB, HpB);

    decode_all<<<GRID, 256, 0, stream>>>(
        HpB, bHB, Wih2, WcB, ws + OFF_BH_, ws + OFF_BG_, ws + OFF_WS_, ws + OFF_OH,
        text, cb, h0, h1, (unsigned short*)ctxB, ws + OFF_PHP,
        (unsigned*)(ws + OFF_BAR), out);
}

// Round 9
// 1370.762 us; speedup vs baseline: 4.4139x; 3.9343x over previous
//
#include <hip/hip_runtime.h>
#include <hip/hip_bf16.h>
#include <math.h>

using bf16 = __hip_bfloat16;

#define NB 1024   // batch
#define NT 64     // encoder length
#define ND 512    // input size D
#define NH 512    // hidden H
#define NC 96     // classes
#define NS 21     // decode steps
#define NDC 608   // D + C
#define NG 2048   // 4H

// ---- workspace layout (float offsets) ----
#define OFF_HPB   0u          /* 16,777,216 : Hp2 bf16 [B*T,H]  (doubled) */
#define OFF_BHB   16777216u   /* 16,777,216 : batch_H bf16    */
#define OFF_C     33554432u   /* 524,288    : c fp32 [B,H]    */
#define OFF_HB16  34078720u   /* 262,144    : h0 bf16 [B,H]   */
#define OFF_CTXB  34865152u   /* 262,144    : ctx bf16 [B,D]  */
#define OFF_WCB   35127296u   /* 163,840  : [2*Wh;Wg;pad] bf16 [640,512]    */
#define OFF_WIH2  35291136u   /* 1,048,576: [Wih[:,:512]|Whh] bf16 [2048,1024] */
#define OFF_HB2   36339712u   /* 262,144  : h1 bf16 [B,H] (ping-pong)       */
#define OFF_WIB   37224448u   /* 131,072  : 2*Wi bf16 [512,512]             */
#define OFF_BH_   38569984u   /* 512  : 2*bh fp32    */
#define OFF_WS_   38570496u   /* 512  : Ws fp32      */
#define OFF_BG_   38571008u   /* 96   : bg fp32      */
#define OFF_OH    38571104u   /* 196,608 : onehotT+bih+bhh fp32 [96][2048]  */
#define OFF_PHP   38767712u   /* 5,242,880 : ph/probs partials fp32 [1024][8][640] */
#define WS_NEED_FLOATS 44010592u
#define WS_NEED_BYTES ((size_t)WS_NEED_FLOATS * 4u)

typedef __attribute__((ext_vector_type(8))) short bf16x8;
typedef __attribute__((ext_vector_type(4))) float f32x4;

__device__ __forceinline__ unsigned short f2bu(float f) {
    unsigned u = __float_as_uint(f);
    unsigned r = (u + 0x7fffu + ((u >> 16) & 1u)) >> 16;  // RNE
    return (unsigned short)r;
}
__device__ __forceinline__ float b2f(short s) {
    return __uint_as_float(((unsigned)(unsigned short)s) << 16);
}
__device__ __forceinline__ float fast_sigmoid(float x) {
    return __builtin_amdgcn_rcpf(1.f + __expf(-x));
}
// tanh(x) = 1 - 2/(e^{2x}+1); saturates correctly without clamping
__device__ __forceinline__ float fast_tanh(float x) {
    return 1.f - 2.f * __builtin_amdgcn_rcpf(1.f + __expf(2.f * x));
}
// tanh from PRE-DOUBLED argument x2 = 2x (weights folded): 1 - 2/(e^{x2}+1)
__device__ __forceinline__ float tanh_pre2(float x2) {
    return 1.f - 2.f * __builtin_amdgcn_rcpf(1.f + __expf(x2));
}

// ---------------- merged conversion: batch_H -> bf16  +  weights prep ----------------
#define BH_BLOCKS 32768u   /* (1024*64*512)/(256*4) */
#define W_ELEMS   2884704u
#define W_BLOCKS  ((W_ELEMS + 255u) / 256u)

__global__ __launch_bounds__(256) void conv_all(
    const float* __restrict__ bHsrc,
    const float* __restrict__ Wi, const float* __restrict__ Wh, const float* __restrict__ bh,
    const float* __restrict__ Ws, const float* __restrict__ Wih, const float* __restrict__ Whh,
    const float* __restrict__ bih, const float* __restrict__ bhh, const float* __restrict__ Wg,
    const float* __restrict__ bg, float* __restrict__ ws) {
    if (blockIdx.x < BH_BLOCKS) {
        unsigned short* dst = (unsigned short*)(ws + OFF_BHB);
        size_t i = ((size_t)blockIdx.x * 256 + threadIdx.x) * 4;
        float4 v = *(const float4*)(bHsrc + i);
        uint2 pk;
        pk.x = (unsigned)f2bu(v.x) | ((unsigned)f2bu(v.y) << 16);
        pk.y = (unsigned)f2bu(v.z) | ((unsigned)f2bu(v.w) << 16);
        *(uint2*)&dst[i] = pk;
        return;
    }
    unsigned i = (blockIdx.x - BH_BLOCKS) * 256u + threadIdx.x;
    if (i >= W_ELEMS) return;
    unsigned short* WiB  = (unsigned short*)(ws + OFF_WIB);
    unsigned short* WcB  = (unsigned short*)(ws + OFF_WCB);
    unsigned short* Wih2 = (unsigned short*)(ws + OFF_WIH2);
    if (i < 262144u) {
        WiB[i] = f2bu(2.f * Wi[i]);           // x2 fold for score tanh
    } else if (i < 524288u) {
        unsigned j = i - 262144u;             // 2*Wh -> combo rows 0..511
        WcB[j] = f2bu(2.f * Wh[j]);
    } else if (i < 573440u) {
        unsigned j = i - 524288u;             // Wg -> combo rows 512..607 (NOT doubled)
        WcB[262144u + j] = f2bu(Wg[j]);
    } else if (i < 589824u) {
        unsigned j = i - 573440u;             // pad rows 608..639 = 0
        WcB[311296u + j] = 0;
    } else if (i < 1638400u) {
        unsigned j = i - 589824u;             // Wih[:, :512] -> Wih2 cols 0..511
        unsigned row = j >> 9, col = j & 511u;
        Wih2[row * 1024u + col] = f2bu(Wih[(size_t)row * NDC + col]);
    } else if (i < 2686976u) {
        unsigned j = i - 1638400u;            // Whh -> Wih2 cols 512..1023
        unsigned row = j >> 9, col = j & 511u;
        Wih2[row * 1024u + 512u + col] = f2bu(Whh[j]);
    } else if (i < 2687488u) {
        unsigned j = i - 2686976u;
        ws[OFF_BH_ + j] = 2.f * bh[j];        // doubled to match Hp2/Wh2
    } else if (i < 2688000u) {
        unsigned j = i - 2687488u;
        ws[OFF_WS_ + j] = Ws[j];
    } else if (i < 2688096u) {
        unsigned j = i - 2688000u;
        ws[OFF_BG_ + j] = bg[j];
    } else {
        unsigned j = i - 2688096u;            // ohb[c][n] = Wih[n][512+c] + bih[n] + bhh[n]
        unsigned c = j >> 11, n = j & 2047u;
        ws[OFF_OH + j] = Wih[(size_t)n * NDC + ND + c] + bih[n] + bhh[n];
    }
}

// ---------------- Hp GEMM (bf16 MFMA, 128x128 tile) ----------------
__global__ __launch_bounds__(256) void hp_gemm(const bf16* __restrict__ A,
                                               const bf16* __restrict__ B,
                                               bf16* __restrict__ outB) {
    __shared__ short As[128 * 40];
    __shared__ short Bs[128 * 40];
    const int tid = threadIdx.x;
    const int wave = tid >> 6, lane = tid & 63;
    const int wrow = wave >> 1, wcol = wave & 1;
    const int quad = lane >> 4, l16 = lane & 15;
    const int m0 = blockIdx.x * 128, n0 = blockIdx.y * 128;
    f32x4 acc[4][4];
    #pragma unroll
    for (int mi = 0; mi < 4; ++mi)
        #pragma unroll
        for (int ni = 0; ni < 4; ++ni) acc[mi][ni] = (f32x4){0.f, 0.f, 0.f, 0.f};
    for (int k0 = 0; k0 < 512; k0 += 32) {
        #pragma unroll
        for (int l = 0; l < 2; ++l) {
            int c = tid + l * 256;
            int row = c >> 2, c8 = c & 3;
            *(uint4*)&As[row * 40 + c8 * 8] =
                *(const uint4*)&A[(size_t)(m0 + row) * 512 + k0 + c8 * 8];
            *(uint4*)&Bs[row * 40 + c8 * 8] =
                *(const uint4*)&B[(size_t)(n0 + row) * 512 + k0 + c8 * 8];
        }
        __syncthreads();
        bf16x8 af[4], bfr[4];
        #pragma unroll
        for (int mi = 0; mi < 4; ++mi)
            af[mi] = *(const bf16x8*)&As[(wrow * 64 + mi * 16 + l16) * 40 + quad * 8];
        #pragma unroll
        for (int ni = 0; ni < 4; ++ni)
            bfr[ni] = *(const bf16x8*)&Bs[(wcol * 64 + ni * 16 + l16) * 40 + quad * 8];
        #pragma unroll
        for (int mi = 0; mi < 4; ++mi)
            #pragma unroll
            for (int ni = 0; ni < 4; ++ni)
                acc[mi][ni] = __builtin_amdgcn_mfma_f32_16x16x32_bf16(af[mi], bfr[ni],
                                                                      acc[mi][ni], 0, 0, 0);
        __syncthreads();
    }
    #pragma unroll
    for (int mi = 0; mi < 4; ++mi)
        #pragma unroll
        for (int ni = 0; ni < 4; ++ni)
            #pragma unroll
            for (int r = 0; r < 4; ++r) {
                int m = m0 + wrow * 64 + mi * 16 + quad * 4 + r;
                int n = n0 + wcol * 64 + ni * 16 + l16;
                outB[(size_t)m * 512 + n] = __float2bfloat16(acc[mi][ni][r]);
            }
}

// ---------------- phase A: ph-sum + probs(s-1) + attention -> ctx ----------------
// 512 threads (8 waves) per block -> 4 blocks/CU * 8 waves = 32 waves/CU (100% occ).
// ph-sum computed ONCE into LDS (coalesced); score tanh uses pre-doubled args.
__global__ __launch_bounds__(512, 8) void attn_phase(
    const bf16* __restrict__ Hp, const bf16* __restrict__ bH,
    const float* __restrict__ bh2, const float* __restrict__ bg,
    const float* __restrict__ Wsv, const float* __restrict__ php,
    unsigned short* __restrict__ ctxB, float* __restrict__ out, int s) {
    const int b = blockIdx.x;
    const int tid = threadIdx.x;
    const int wave = tid >> 6, lane = tid & 63;
    __shared__ float tr[64 * 65];    // 16,640 B : tr[t][lane] partials
    __shared__ float red[8 * 520];   // 16,640 B : per-wave partials
    __shared__ float phs[512];       // doubled ph, shared across waves
    __shared__ float salpha[64];
    // --- ph-sum into LDS (each thread one h), + probs(s-1) emit ---
    {
        float v = bh2[tid];
        if (s > 0) {
            #pragma unroll
            for (int p = 0; p < 8; ++p)
                v += php[((size_t)b * 8 + p) * 640 + tid];
        }
        phs[tid] = v;
        if (s > 0 && tid < NC) {
            float pv = bg[tid];
            #pragma unroll
            for (int p = 0; p < 8; ++p)
                pv += php[((size_t)b * 8 + p) * 640 + 512 + tid];
            out[(size_t)b * (NS * NC) + (s - 1) * NC + tid] = pv;
        }
    }
    __syncthreads();
    float ph8[8], ws8[8];
    #pragma unroll
    for (int j = 0; j < 8; ++j) ph8[j] = phs[lane * 8 + j];
    {
        float4 wsa = *(const float4*)(Wsv + lane * 8);
        float4 wsb = *(const float4*)(Wsv + lane * 8 + 4);
        ws8[0] = wsa.x; ws8[1] = wsa.y; ws8[2] = wsa.z; ws8[3] = wsa.w;
        ws8[4] = wsb.x; ws8[5] = wsb.y; ws8[6] = wsb.z; ws8[7] = wsb.w;
    }
    // --- scores: wave w owns t = w*8..w*8+7 ---
    const bf16* hpb = Hp + ((size_t)b * NT + wave * 8) * NH + lane * 8;
    #pragma unroll
    for (int i = 0; i < 8; ++i) {
        bf16x8 hv = *(const bf16x8*)(hpb + (size_t)i * NH);
        float sc = 0.f;
        #pragma unroll
        for (int j = 0; j < 8; ++j) sc += tanh_pre2(b2f(hv[j]) + ph8[j]) * ws8[j];
        tr[(wave * 8 + i) * 65 + lane] = sc;
    }
    __syncthreads();
    {   // partial reduce: thread (t, chunk) sums 8
        int t = tid & 63, ch = tid >> 6;
        const float* row = &tr[t * 65 + ch * 8];
        float pp = 0.f;
        #pragma unroll
        for (int j = 0; j < 8; ++j) pp += row[j];
        red[ch * 520 + t] = pp;
    }
    __syncthreads();
    if (tid < NT) {
        float e = 0.f;
        #pragma unroll
        for (int ch = 0; ch < 8; ++ch) e += red[ch * 520 + tid];
        float m = e;
        #pragma unroll
        for (int off = 32; off > 0; off >>= 1) m = fmaxf(m, __shfl_xor(m, off, 64));
        float exv = __expf(e - m);
        float ssum = exv;
        #pragma unroll
        for (int off = 32; off > 0; off >>= 1) ssum += __shfl_xor(ssum, off, 64);
        salpha[tid] = exv / ssum;
    }
    __syncthreads();
    {   // context: wave w accumulates t in [w*8, w*8+8); lane owns d = lane*8..+7
        const bf16* bhp = bH + ((size_t)b * NT + wave * 8) * ND + lane * 8;
        float a8[8];
        #pragma unroll
        for (int u = 0; u < 8; ++u) a8[u] = 0.f;
        #pragma unroll
        for (int i = 0; i < 8; ++i) {
            float al = salpha[wave * 8 + i];
            bf16x8 v = *(const bf16x8*)(bhp + (size_t)i * ND);
            #pragma unroll
            for (int u = 0; u < 8; ++u) a8[u] = fmaf(al, b2f(v[u]), a8[u]);
        }
        #pragma unroll
        for (int u = 0; u < 8; ++u) red[wave * 520 + lane * 8 + u] = a8[u];
    }
    __syncthreads();
    {   // final ctx: thread tid owns d = tid
        float sum = 0.f;
        #pragma unroll
        for (int w = 0; w < 8; ++w) sum += red[w * 520 + tid];
        ctxB[(size_t)b * ND + tid] = f2bu(sum);
    }
}

// ---------------- phase B: gates GEMM (K=1024, double-buffered) + LSTM + mini-combo --------
// grid 256 = 8 kp-tiles (XCD-aligned: p = bid & 7) x 32 m-tiles.
__global__ __launch_bounds__(256) void gates_phase(
    const bf16* __restrict__ ctxB, const bf16* __restrict__ hIn,
    const bf16* __restrict__ Wih2, const bf16* __restrict__ WcB,
    const float* __restrict__ ohb, const int* __restrict__ text, int s,
    float* __restrict__ c, unsigned short* __restrict__ hOut,
    float* __restrict__ php) {
    __shared__ float smem[12672];                 // 50,688 B
    short* lds = (short*)smem;                    // buf k: As at k*11520, Bs at k*11520+1280
    float* ex = smem;                             // [4][32][65] after the k-loop
    short* hlds = (short*)((char*)smem + 46080);  // [32][72] h tile bf16
    const int tid = threadIdx.x;
    const int wave = tid >> 6, lane = tid & 63;
    const int quad = lane >> 4, l16 = lane & 15;
    const int g = wave;
    const int m0 = (blockIdx.x >> 3) * 32;
    const int p = blockIdx.x & 7;                 // == XCD id under round-robin dispatch
    const int kp0 = p * 64;
    const int arow = tid >> 2, ac8 = tid & 3;     // A staging coords (tid<128)
    const short* Wih2s = (const short*)Wih2;
    f32x4 acc[2][4];
    #pragma unroll
    for (int mi = 0; mi < 2; ++mi)
        #pragma unroll
        for (int ni = 0; ni < 4; ++ni) acc[mi][ni] = (f32x4){0.f, 0.f, 0.f, 0.f};

    uint4 rb[4]; uint4 ra;
#define STAGE_LOAD(K0)                                                         \
    {                                                                          \
        _Pragma("unroll")                                                      \
        for (int l = 0; l < 4; ++l) {                                          \
            int j = tid + l * 256;                                             \
            int row = j >> 2, c8 = j & 3;                                      \
            int brow = (row >> 6) * 512 + kp0 + (row & 63);                    \
            rb[l] = *(const uint4*)&Wih2s[(size_t)brow * 1024 + (K0) + c8 * 8];\
        }                                                                      \
        if (tid < 128) {                                                       \
            const short* srcA = ((K0) < 512)                                   \
                ? (const short*)ctxB + (size_t)(m0 + arow) * 512 + (K0) + ac8 * 8          \
                : (const short*)hIn + (size_t)(m0 + arow) * 512 + ((K0) - 512) + ac8 * 8;  \
            ra = *(const uint4*)srcA;                                          \
        }                                                                      \
    }
#define STAGE_WRITE(BUF)                                                       \
    {                                                                          \
        _Pragma("unroll")                                                      \
        for (int l = 0; l < 4; ++l) {                                          \
            int j = tid + l * 256;                                             \
            int row = j >> 2, c8 = j & 3;                                      \
            *(uint4*)&lds[(BUF) * 11520 + 1280 + row * 40 + c8 * 8] = rb[l];   \
        }                                                                      \
        if (tid < 128) *(uint4*)&lds[(BUF) * 11520 + arow * 40 + ac8 * 8] = ra;\
    }

    STAGE_LOAD(0);
    STAGE_WRITE(0);
    __syncthreads();
    for (int it = 0; it < 32; ++it) {
        const int buf = it & 1;
        if (it + 1 < 32) STAGE_LOAD((it + 1) * 32);
        bf16x8 af[2], bfr[4];
        #pragma unroll
        for (int mi = 0; mi < 2; ++mi)
            af[mi] = *(const bf16x8*)&lds[buf * 11520 + (mi * 16 + l16) * 40 + quad * 8];
        #pragma unroll
        for (int ni = 0; ni < 4; ++ni)
            bfr[ni] = *(const bf16x8*)&lds[buf * 11520 + 1280 +
                                           (g * 64 + ni * 16 + l16) * 40 + quad * 8];
        #pragma unroll
        for (int mi = 0; mi < 2; ++mi)
            #pragma unroll
            for (int ni = 0; ni < 4; ++ni)
                acc[mi][ni] = __builtin_amdgcn_mfma_f32_16x16x32_bf16(
                    af[mi], bfr[ni], acc[mi][ni], 0, 0, 0);
        if (it + 1 < 32) STAGE_WRITE(buf ^ 1);
        __syncthreads();
    }
#undef STAGE_LOAD
#undef STAGE_WRITE
    #pragma unroll
    for (int mi = 0; mi < 2; ++mi)
        #pragma unroll
        for (int ni = 0; ni < 4; ++ni)
            #pragma unroll
            for (int r = 0; r < 4; ++r) {
                int ml = mi * 16 + quad * 4 + r;
                int nl = ni * 16 + l16;
                ex[g * 2080 + ml * 65 + nl] = acc[mi][ni][r];
            }
    __syncthreads();
    #pragma unroll 1
    for (int t = 0; t < 8; ++t) {
        int idx = tid + t * 256;
        int ml = idx >> 6, kl = idx & 63;
        int m = m0 + ml, kp = kp0 + kl;
        int tb = text[m * NS + s];
        const float* oh = ohb + (size_t)tb * NG;   // onehot + bih + bhh
        float ig = fast_sigmoid(ex[0 * 2080 + ml * 65 + kl] + oh[kp]);
        float fg = fast_sigmoid(ex[1 * 2080 + ml * 65 + kl] + oh[NH + kp]);
        float gg = fast_tanh(ex[2 * 2080 + ml * 65 + kl] + oh[2 * NH + kp]);
        float og = fast_sigmoid(ex[3 * 2080 + ml * 65 + kl] + oh[3 * NH + kp]);
        float cn = fg * c[(size_t)m * NH + kp] + ig * gg;
        float hn = og * fast_tanh(cn);
        c[(size_t)m * NH + kp] = cn;
        unsigned short hb = f2bu(hn);
        hOut[(size_t)m * NH + kp] = hb;
        hlds[ml * 72 + kl] = (short)hb;
    }
    __syncthreads();
    // mini-GEMM: php[m][p][0..640) = h_tile(32x64k) @ WcB[:,kp-slice]^T
    // rows 0..511 of WcB are 2*Wh -> partials come out pre-doubled for the score tanh
    #pragma unroll 1
    for (int nf = 0; nf < 10; ++nf) {
        int n0 = wave * 160 + nf * 16;
        f32x4 a0 = (f32x4){0.f, 0.f, 0.f, 0.f}, a1 = a0;
        #pragma unroll
        for (int ks = 0; ks < 2; ++ks) {
            bf16x8 bfrg = *(const bf16x8*)((const short*)WcB +
                (size_t)(n0 + l16) * 512 + kp0 + ks * 32 + quad * 8);
            bf16x8 af0 = *(const bf16x8*)&hlds[l16 * 72 + ks * 32 + quad * 8];
            bf16x8 af1 = *(const bf16x8*)&hlds[(16 + l16) * 72 + ks * 32 + quad * 8];
            a0 = __builtin_amdgcn_mfma_f32_16x16x32_bf16(af0, bfrg, a0, 0, 0, 0);
            a1 = __builtin_amdgcn_mfma_f32_16x16x32_bf16(af1, bfrg, a1, 0, 0, 0);
        }
        #pragma unroll
        for (int r = 0; r < 4; ++r) {
            php[((size_t)(m0 + quad * 4 + r) * 8 + p) * 640 + n0 + l16] = a0[r];
            php[((size_t)(m0 + 16 + quad * 4 + r) * 8 + p) * 640 + n0 + l16] = a1[r];
        }
    }
}

// ---------------- final: probs row 20 from the last step's ph partials ----------------
__global__ __launch_bounds__(128) void probs_final(const float* __restrict__ php,
                                                   const float* __restrict__ bg,
                                                   float* __restrict__ out) {
    const int b = blockIdx.x;
    const int tid = threadIdx.x;
    if (tid < NC) {
        float v = bg[tid];
        #pragma unroll
        for (int p = 0; p < 8; ++p) v += php[((size_t)b * 8 + p) * 640 + 512 + tid];
        out[(size_t)b * (NS * NC) + 20 * NC + tid] = v;
    }
}

extern "C" void kernel_launch(void* const* d_in, const int* in_sizes, int n_in,
                              void* d_out, int out_size, void* d_ws, size_t ws_size,
                              hipStream_t stream) {
    if (ws_size < WS_NEED_BYTES) {
        hipMemsetAsync(d_out, 0x7F, (size_t)out_size * 4, stream);
        return;
    }
    float* ws = (float*)d_ws;
    bf16* HpB  = (bf16*)(ws + OFF_HPB);
    bf16* bHB  = (bf16*)(ws + OFF_BHB);
    float* cb  = ws + OFF_C;
    bf16* h0   = (bf16*)(ws + OFF_HB16);
    bf16* h1   = (bf16*)(ws + OFF_HB2);
    bf16* ctxB = (bf16*)(ws + OFF_CTXB);
    bf16* WcB  = (bf16*)(ws + OFF_WCB);
    bf16* Wih2 = (bf16*)(ws + OFF_WIH2);
    bf16* WiB  = (bf16*)(ws + OFF_WIB);
    const int* text = (const int*)d_in[1];
    float* out = (float*)d_out;

    conv_all<<<BH_BLOCKS + W_BLOCKS, 256, 0, stream>>>(
        (const float*)d_in[0],
        (const float*)d_in[2], (const float*)d_in[3], (const float*)d_in[4],
        (const float*)d_in[5], (const float*)d_in[6], (const float*)d_in[7],
        (const float*)d_in[8], (const float*)d_in[9], (const float*)d_in[10],
        (const float*)d_in[11], ws);
    // zero c (fp32) + h0 (bf16): contiguous from OFF_C
    hipMemsetAsync(cb, 0, (size_t)786432 * 4, stream);

    // Hp2(bf16) = batch_H @ (2*Wi)^T
    hp_gemm<<<dim3(NB * NT / 128, ND / 128), 256, 0, stream>>>(bHB, WiB, HpB);

    for (int s = 0; s < NS; ++s) {
        bf16* hcur = (s & 1) ? h1 : h0;
        bf16* hnext = (s & 1) ? h0 : h1;
        attn_phase<<<NB, 512, 0, stream>>>(HpB, bHB, ws + OFF_BH_, ws + OFF_BG_,
                                           ws + OFF_WS_, ws + OFF_PHP,
                                           (unsigned short*)ctxB, out, s);
        gates_phase<<<dim3(256), 256, 0, stream>>>(
            ctxB, hcur, Wih2, WcB, ws + OFF_OH, text, s, cb,
            (unsigned short*)hnext, ws + OFF_PHP);
    }
    probs_final<<<NB, 128, 0, stream>>>(ws + OFF_PHP, ws + OFF_BG_, out);
}